// Round 7
// baseline (584.190 us; speedup 1.0000x reference)
//
#include <hip/hip_runtime.h>
#include <math.h>

typedef unsigned short u16;
typedef __bf16 bf16_t;
typedef u16 u16x4 __attribute__((ext_vector_type(4)));
typedef u16 u16x8 __attribute__((ext_vector_type(8)));
typedef bf16_t bf16x8 __attribute__((ext_vector_type(8)));
typedef float f32x4 __attribute__((ext_vector_type(4)));

__device__ __forceinline__ float bf2f(u16 v) {
    union { unsigned u; float f; } x; x.u = ((unsigned)v) << 16; return x.f;
}
// Manual RNE f32->bf16 (exact baseline-522 behavior).
__device__ __forceinline__ u16 f2bf(float f) {
    union { float f; unsigned u; } x; x.f = f;
    unsigned u = x.u;
    return (u16)((u + 0x7fffu + ((u >> 16) & 1u)) >> 16);
}

// Async global->LDS DMA, 16B per lane. LDS dest = wave-uniform base + lane*16
// (hardware-defined); global src is per-lane.
__device__ __forceinline__ void gload16(const u16* g, u16* l) {
    __builtin_amdgcn_global_load_lds(
        (const __attribute__((address_space(1))) void*)g,
        (__attribute__((address_space(3))) void*)l,
        16, 0, 0);
}

// ---------------------------------------------------------------------------
// Runtime dtype detector (probe = Wq). bf16: high byte of each u32 is sign/exp
// in [0x38,0x3F]; fp32: uniform mantissa byte. 64-lane majority => exact.
// ---------------------------------------------------------------------------
__device__ __forceinline__ bool is_bf16_input(const unsigned* __restrict__ probe) {
    unsigned w = probe[(threadIdx.x & 63) * 32771 + 7];
    unsigned b7 = (w >> 8) & 0x7f;
    bool hit = (b7 >= 0x38) && (b7 <= 0x3f);
    return __builtin_popcountll(__ballot(hit)) >= 32;
}

__global__ __launch_bounds__(256) void convert_kernel(
    const void* __restrict__ src, u16* __restrict__ dst, int n,
    const unsigned* __restrict__ probe)
{
    bool bf = is_bf16_input(probe);
    int i = (blockIdx.x * 256 + threadIdx.x) * 8;
    if (i >= n) return;
    if (bf) {
        *(u16x8*)&dst[i] = *(const u16x8*)&((const u16*)src)[i];
    } else {
        const float* s = (const float*)src + i;
        u16x8 o;
#pragma unroll
        for (int j = 0; j < 8; j++) o[j] = f2bf(s[j]);
        *(u16x8*)&dst[i] = o;
    }
}

__global__ __launch_bounds__(256) void tconv_kernel(
    const void* __restrict__ in, u16* __restrict__ out, int R, int C,
    const unsigned* __restrict__ probe)
{
    bool bf = is_bf16_input(probe);
    __shared__ u16 t[32][33];
    int x = threadIdx.x & 31, y = threadIdx.x >> 5;
    int bx = blockIdx.x * 32, by = blockIdx.y * 32;
    if (bf) {
        const u16* s = (const u16*)in;
#pragma unroll
        for (int i = 0; i < 32; i += 8)
            t[y + i][x] = s[(size_t)(by + y + i) * C + bx + x];
    } else {
        const float* s = (const float*)in;
#pragma unroll
        for (int i = 0; i < 32; i += 8)
            t[y + i][x] = f2bf(s[(size_t)(by + y + i) * C + bx + x]);
    }
    __syncthreads();
#pragma unroll
    for (int i = 0; i < 32; i += 8)
        out[(size_t)(bx + y + i) * R + by + x] = t[x][y + i];
}

// Transpose with separate input row stride (pulls V columns out of fused QKV).
__global__ __launch_bounds__(256) void transpose_kernel(
    const u16* __restrict__ in, u16* __restrict__ out, int R, int LD)
{
    __shared__ u16 t[32][33];
    int x = threadIdx.x & 31, y = threadIdx.x >> 5;
    int bx = blockIdx.x * 32, by = blockIdx.y * 32;
#pragma unroll
    for (int i = 0; i < 32; i += 8)
        t[y + i][x] = in[(size_t)(by + y + i) * LD + bx + x];
    __syncthreads();
#pragma unroll
    for (int i = 0; i < 32; i += 8)
        out[(size_t)(bx + y + i) * R + by + x] = t[x][y + i];
}

// ---------------------------------------------------------------------------
// GEMM: C[M,N] = (A[M,K] @ BT[N,K]^T + bias[N]) * scale
// global_load_lds width=16 staging into linear [128][32] LDS tiles.
// Bias is read RAW (bf16 or f32 decided by probe) -- the 4 tiny bias-convert
// launches are folded into this epilogue. For the fused-QKV call the bias is
// segmented: cols [0,2048)=bias0(bq), [2048,2560)=bias1(bk), [2560,3072)=
// bias2(bv). out_native=1 => output dtype follows input dtype (final GEMM).
// ---------------------------------------------------------------------------
__global__ __launch_bounds__(256) void gemm_bias_kernel(
    const u16* __restrict__ A, const u16* __restrict__ BT,
    const void* __restrict__ bias0, const void* __restrict__ bias1,
    const void* __restrict__ bias2, void* __restrict__ Cout,
    int M, int N, int K, const unsigned* __restrict__ probe,
    int out_native, float scale)
{
    __shared__ __align__(16) u16 As[128 * 32];
    __shared__ __align__(16) u16 Bs[128 * 32];
    const int tid  = threadIdx.x;
    const int lane = tid & 63, wave = tid >> 6;
    const int quad = lane >> 4, li = lane & 15;
    const int bm = blockIdx.x * 128, bn = blockIdx.y * 128;
    const int wm = (wave >> 1) * 64, wn = (wave & 1) * 64;
    const int lrow = lane >> 2;          // 0..15 row within 16-row chunk
    const int lcol = (lane & 3) * 8;     // u16 col offset

    f32x4 acc[4][4] = {};

    for (int k0 = 0; k0 < K; k0 += 32) {
#pragma unroll
        for (int j = 0; j < 2; j++) {
            int c = wave * 2 + j;
            int row = c * 16 + lrow;
            gload16(&A [(size_t)(bm + row) * K + k0 + lcol], &As[c * 16 * 32]);
            gload16(&BT[(size_t)(bn + row) * K + k0 + lcol], &Bs[c * 16 * 32]);
        }
        __syncthreads();   // vmcnt drained at barrier: tiles ready
        bf16x8 af[4], bfr[4];
#pragma unroll
        for (int i = 0; i < 4; i++)
            af[i]  = *(const bf16x8*)&As[(wm + i * 16 + li) * 32 + quad * 8];
#pragma unroll
        for (int i = 0; i < 4; i++)
            bfr[i] = *(const bf16x8*)&Bs[(wn + i * 16 + li) * 32 + quad * 8];
#pragma unroll
        for (int mt = 0; mt < 4; mt++)
#pragma unroll
            for (int nt = 0; nt < 4; nt++)
                acc[mt][nt] = __builtin_amdgcn_mfma_f32_16x16x32_bf16(
                    af[mt], bfr[nt], acc[mt][nt], 0, 0, 0);
        __syncthreads();
    }

    const bool bf_in = is_bf16_input(probe);
    const bool out_bf = out_native ? bf_in : true;
#pragma unroll
    for (int nt = 0; nt < 4; nt++) {
        int col = bn + wn + nt * 16 + li;
        const void* bp; int bc;
        if (col < 2048)      { bp = bias0; bc = col; }
        else if (col < 2560) { bp = bias1; bc = col - 2048; }
        else                 { bp = bias2; bc = col - 2560; }
        float bb = bf_in ? bf2f(((const u16*)bp)[bc]) : ((const float*)bp)[bc];
        if (out_bf) {
            u16* C16 = (u16*)Cout;
#pragma unroll
            for (int mt = 0; mt < 4; mt++)
#pragma unroll
                for (int r = 0; r < 4; r++) {
                    int row = bm + wm + mt * 16 + quad * 4 + r;
                    C16[(size_t)row * N + col] = f2bf((acc[mt][nt][r] + bb) * scale);
                }
        } else {
            float* Cf = (float*)Cout;
#pragma unroll
            for (int mt = 0; mt < 4; mt++)
#pragma unroll
                for (int r = 0; r < 4; r++) {
                    int row = bm + wm + mt * 16 + quad * 4 + r;
                    Cf[(size_t)row * N + col] = (acc[mt][nt][r] + bb) * scale;
                }
        }
    }
}

// ---------------------------------------------------------------------------
// Flash attention v9 = v3 body byte-identical, split-key schedule.
// The 165 µs kernel's wall time = critical path of the heavy diagonal blocks
// (Occ 10.5%, 512 blocks at 2/CU, heaviest = 64 iters of a ~4850cy latency
// chain). Split-key multiplies parallelism WITHOUT touching the proven inner
// loop (v4-v7 inner rewrites: 0/4):
//   - units per (h,b): qt 0..9 -> 1 unit (keys [0,(qt+1)*128), direct O write,
//     identical to today); qt 10..15 -> 2 units (keys split at halfway tile),
//     each writes unnormalized f32 partials O_i + per-row m_i, l_i.
//   - grid (22,16,2) = 704 balanced blocks (max 40 iters vs 64); at 124 VGPR
//     (launch_bounds(256,4) caps at 128) and 29 KB LDS -> 4 blocks/CU -> ALL
//     blocks co-resident at launch, ~11 waves/CU (vs 3.4).
//   - combine_kernel merges the 2 partials per split q-tile.
// Partials live in the DEAD Xc+WqkvT workspace region (combine runs before
// the Wo transpose reclaims it). No ws growth, f32 precision.
// Q:[B*S,3072]  K:[B*S,3072]@+2048  VT:[512,B*S]  O:[B*S,2048].
// ---------------------------------------------------------------------------
__global__ __launch_bounds__(256, 4) void flash_kernel(
    const u16* __restrict__ Q, const u16* __restrict__ Kg,
    const u16* __restrict__ VT, u16* __restrict__ O,
    float* __restrict__ PO, float* __restrict__ PM, float* __restrict__ PL)
{
    constexpr int S = 2048, D = 2048, DH = 128, QKSTR = 3072;
    constexpr float SCALE = 0.08838834764831845f;  // 1/sqrt(128)
    __shared__ __align__(16) u16 Ks[32 * 136];   // [key][dh]   8704 B
    __shared__ __align__(16) u16 Vt[128 * 40];   // [dh][key]  10240 B
    __shared__ __align__(16) u16 Pw[4][32 * 40]; // [qrow][key] 10240 B

    const int tid  = threadIdx.x;
    const int wave = tid >> 6, lane = tid & 63;
    const int quad = lane >> 4, li = lane & 15;
    const int uu = blockIdx.x, h = blockIdx.y, b = blockIdx.z;
    // unit decode: uu 0..9 -> unsplit qt=uu; uu 10..21 -> qt=10+(uu-10)/2,
    // chunk cc=(uu-10)&1 with keys split at the halfway tile.
    const int split = (uu >= 10) ? 1 : 0;
    const int qt = split ? (10 + ((uu - 10) >> 1)) : uu;
    const int cc = split ? ((uu - 10) & 1) : 0;
    const int tiles = qt + 1;
    const int kmid = (tiles >> 1) * 128;
    const int kstart = cc ? kmid : 0;
    const int kend = (split && !cc) ? kmid : tiles * 128;
    const int g = h >> 2;
    const int q0w = qt * 128 + wave * 32;        // this wave's first q-row

    const u16* Qb = Q  + (size_t)b * S * QKSTR;
    const u16* Kb = Kg + (size_t)b * S * QKSTR;
    const u16* Vg = VT + (size_t)g * DH * (2 * S) + (size_t)b * S;

    // Q fragments: B-operand, rows q0w + m*16 + li, k = quad*8 (+c*32)
    bf16x8 qf[2][4];
#pragma unroll
    for (int m = 0; m < 2; m++)
#pragma unroll
        for (int c = 0; c < 4; c++)
            qf[m][c] = *(const bf16x8*)&Qb[(size_t)(q0w + m * 16 + li) * QKSTR
                                           + h * DH + c * 32 + quad * 8];

    f32x4 oacc[2][8] = {};
    float mr[2] = { -INFINITY, -INFINITY };
    float lr[2] = { 0.f, 0.f };

    // --- register prefetch of tile at kstart ---
    u16x8 kreg[2], vreg[2];
#pragma unroll
    for (int ch = 0; ch < 2; ch++) {
        int idx = tid + ch * 256;
        kreg[ch] = *(const u16x8*)&Kb[(size_t)(kstart + (idx >> 4)) * QKSTR
                                      + g * DH + (idx & 15) * 8];
        vreg[ch] = *(const u16x8*)&Vg[(size_t)(idx >> 2) * (2 * S)
                                      + kstart + (idx & 3) * 8];
    }

    for (int kc = kstart; kc < kend; kc += 32) {
        // commit prefetched tile to LDS
#pragma unroll
        for (int ch = 0; ch < 2; ch++) {
            int idx = tid + ch * 256;
            *(u16x8*)&Ks[(idx >> 4) * 136 + (idx & 15) * 8] = kreg[ch];
            *(u16x8*)&Vt[(idx >> 2) * 40  + (idx & 3) * 8]  = vreg[ch];
        }
        __syncthreads();

        // issue prefetch for next tile (overlaps with compute below)
        int kn = kc + 32;
        if (kn < kend) {
#pragma unroll
            for (int ch = 0; ch < 2; ch++) {
                int idx = tid + ch * 256;
                kreg[ch] = *(const u16x8*)&Kb[(size_t)(kn + (idx >> 4)) * QKSTR
                                              + g * DH + (idx & 15) * 8];
                vreg[ch] = *(const u16x8*)&Vg[(size_t)(idx >> 2) * (2 * S)
                                              + kn + (idx & 3) * 8];
            }
        }

        if (kc <= q0w) {   // causal: tiles with kc > q0w are fully masked
            // S^T = K · Q^T : sacc[m][t], C row = key (quad*4+r), col = qrow (li)
            f32x4 sacc[2][2] = {};
#pragma unroll
            for (int t = 0; t < 2; t++)
#pragma unroll
                for (int c = 0; c < 4; c++) {
                    bf16x8 kf = *(const bf16x8*)&Ks[(t * 16 + li) * 136 + c * 32 + quad * 8];
#pragma unroll
                    for (int m = 0; m < 2; m++)
                        sacc[m][t] = __builtin_amdgcn_mfma_f32_16x16x32_bf16(
                            kf, qf[m][c], sacc[m][t], 0, 0, 0);
                }

            float alpha_b[2][4];
#pragma unroll
            for (int m = 0; m < 2; m++) {
                int row = q0w + m * 16 + li;
                f32x4 s0 = sacc[m][0] * SCALE;
                f32x4 s1 = sacc[m][1] * SCALE;
#pragma unroll
                for (int r = 0; r < 4; r++) {
                    int k0 = kc + quad * 4 + r;
                    if (k0 > row)      s0[r] = -INFINITY;
                    if (k0 + 16 > row) s1[r] = -INFINITY;
                }
                float mx = fmaxf(fmaxf(fmaxf(s0[0], s0[1]), fmaxf(s0[2], s0[3])),
                                 fmaxf(fmaxf(s1[0], s1[1]), fmaxf(s1[2], s1[3])));
                mx = fmaxf(mx, __shfl_xor(mx, 16));
                mx = fmaxf(mx, __shfl_xor(mx, 32));
                float mnew = fmaxf(mr[m], mx);
                float al = __expf(mr[m] - mnew);
                mr[m] = mnew;
                f32x4 p0, p1;
                float ps = 0.f;
#pragma unroll
                for (int r = 0; r < 4; r++) {
                    p0[r] = __expf(s0[r] - mnew);
                    p1[r] = __expf(s1[r] - mnew);
                    ps += p0[r] + p1[r];
                }
                ps += __shfl_xor(ps, 16);
                ps += __shfl_xor(ps, 32);
                lr[m] = lr[m] * al + ps;
                u16x4 c0, c1;
#pragma unroll
                for (int r = 0; r < 4; r++) { c0[r] = f2bf(p0[r]); c1[r] = f2bf(p1[r]); }
                *(u16x4*)&Pw[wave][(m * 16 + li) * 40 + quad * 4]      = c0;
                *(u16x4*)&Pw[wave][(m * 16 + li) * 40 + 16 + quad * 4] = c1;
#pragma unroll
                for (int r = 0; r < 4; r++)
                    alpha_b[m][r] = __shfl(al, quad * 4 + r, 16);
            }

            // rescale O accumulators
#pragma unroll
            for (int m = 0; m < 2; m++)
#pragma unroll
                for (int dt = 0; dt < 8; dt++)
#pragma unroll
                    for (int r = 0; r < 4; r++)
                        oacc[m][dt][r] *= alpha_b[m][r];

            // drain P stores (same wave) before vector re-read
            asm volatile("s_waitcnt lgkmcnt(0)" ::: "memory");
            union { u16x8 u; bf16x8 bv; } pc0, pc1;
            pc0.u = *(const u16x8*)&Pw[wave][(0 * 16 + li) * 40 + quad * 8];
            pc1.u = *(const u16x8*)&Pw[wave][(1 * 16 + li) * 40 + quad * 8];
            bf16x8 pf[2] = { pc0.bv, pc1.bv };

            // O += P · V
#pragma unroll
            for (int dt = 0; dt < 8; dt++) {
                bf16x8 vf = *(const bf16x8*)&Vt[(dt * 16 + li) * 40 + quad * 8];
#pragma unroll
                for (int m = 0; m < 2; m++)
                    oacc[m][dt] = __builtin_amdgcn_mfma_f32_16x16x32_bf16(
                        pf[m], vf, oacc[m][dt], 0, 0, 0);
            }
        }
        __syncthreads();
    }

    if (!split) {
        u16* Ob = O + (size_t)b * S * D;
#pragma unroll
        for (int m = 0; m < 2; m++) {
#pragma unroll
            for (int r = 0; r < 4; r++) {
                float linv = 1.0f / __shfl(lr[m], quad * 4 + r, 16);
                int row = q0w + m * 16 + quad * 4 + r;
#pragma unroll
                for (int dt = 0; dt < 8; dt++)
                    Ob[(size_t)row * D + h * DH + dt * 16 + li] =
                        f2bf(oacc[m][dt][r] * linv);
            }
        }
    } else {
        // partial epilogue: unnormalized O (f32) + per-row m, l
        const int gu = (b * 16 + h) * 12 + (qt - 10) * 2 + cc;
        float* POu = PO + (size_t)gu * 16384;
#pragma unroll
        for (int m = 0; m < 2; m++)
#pragma unroll
            for (int r = 0; r < 4; r++) {
                int rl = wave * 32 + m * 16 + quad * 4 + r;
#pragma unroll
                for (int dt = 0; dt < 8; dt++)
                    POu[rl * 128 + dt * 16 + li] = oacc[m][dt][r];
            }
        if (quad == 0) {
#pragma unroll
            for (int m = 0; m < 2; m++) {
                int rl = wave * 32 + m * 16 + li;   // mr/lr are per-li rows
                PM[gu * 128 + rl] = mr[m];
                PL[gu * 128 + rl] = lr[m];
            }
        }
    }
}

// ---------------------------------------------------------------------------
// Merge the 2 key-chunk partials of each split q-tile (qt 10..15):
// O = (e^{m0-M} O_0 + e^{m1-M} O_1) / (e^{m0-M} l_0 + e^{m1-M} l_1).
// Grid (6, 16, 2) x 256 thr; thread -> (row = t>>1, col-half = (t&1)*64).
// ---------------------------------------------------------------------------
__global__ __launch_bounds__(256) void combine_kernel(
    const float* __restrict__ PO, const float* __restrict__ PM,
    const float* __restrict__ PL, u16* __restrict__ O)
{
    constexpr int S = 2048, D = 2048;
    const int qt = 10 + blockIdx.x, h = blockIdx.y, b = blockIdx.z;
    const int g0 = (b * 16 + h) * 12 + blockIdx.x * 2;
    const int t = threadIdx.x;
    const int row = t >> 1, half = (t & 1) * 64;

    float m0 = PM[g0 * 128 + row], m1 = PM[(g0 + 1) * 128 + row];
    float l0 = PL[g0 * 128 + row], l1 = PL[(g0 + 1) * 128 + row];
    float M = fmaxf(m0, m1);
    float w0 = __expf(m0 - M), w1 = __expf(m1 - M);
    float linv = 1.0f / (l0 * w0 + l1 * w1);

    const float* p0 = PO + (size_t)g0 * 16384 + row * 128 + half;
    const float* p1 = p0 + 16384;
    u16* out = O + (size_t)(b * S + qt * 128 + row) * D + h * 128 + half;
#pragma unroll
    for (int j = 0; j < 64; j += 4) {
        f32x4 a = *(const f32x4*)&p0[j];
        f32x4 c = *(const f32x4*)&p1[j];
        u16x4 o;
#pragma unroll
        for (int e = 0; e < 4; e++) o[e] = f2bf((a[e] * w0 + c[e] * w1) * linv);
        *(u16x4*)&out[j] = o;
    }
}

// ---------------------------------------------------------------------------
extern "C" void kernel_launch(void* const* d_in, const int* in_sizes, int n_in,
                              void* d_out, int out_size, void* d_ws, size_t ws_size,
                              hipStream_t stream)
{
    const void* X  = d_in[0];
    const void* Wq = d_in[3];
    const void* bq = d_in[4];
    const void* Wk = d_in[5];
    const void* bk = d_in[6];
    const void* Wv = d_in[7];
    const void* bv = d_in[8];
    const void* Wo = d_in[9];
    const void* bo = d_in[10];
    const unsigned* probe = (const unsigned*)d_in[3];

    u16* ws    = (u16*)d_ws;
    u16* Xc    = ws;                     // [0, 8388608)        X bf16
    u16* WqkvT = Xc    + 8388608;        // [8388608, 14680064) Wqkv^T / later WoT
    u16* QKV   = WqkvT + 6291456;        // [14680064, 27262976)
    u16* VTb   = QKV   + 12582912;       // [27262976, 29360128)
    u16* Ob    = VTb   + 2097152;        // [29360128, 37748736)
    // Partials overlay the DEAD Xc+WqkvT region during flash+combine:
    // PO f32[384*16384] + PM f32[384*128] + PL f32[384*128] = 12,779,520 u16.
    float* PO  = (float*)ws;
    float* PM  = PO + 384 * 16384;
    float* PL  = PM + 384 * 128;

    convert_kernel<<<4096, 256, 0, stream>>>(X, Xc, 8388608, probe);

    // Wqkv^T[3072][2048]: rows 0..2047 = Wq^T, 2048..2559 = Wk^T, 2560..3071 = Wv^T
    tconv_kernel<<<dim3(64, 64), 256, 0, stream>>>(Wq, WqkvT,               2048, 2048, probe);
    tconv_kernel<<<dim3(16, 64), 256, 0, stream>>>(Wk, WqkvT + 2048 * 2048, 2048, 512,  probe);
    tconv_kernel<<<dim3(16, 64), 256, 0, stream>>>(Wv, WqkvT + 2560 * 2048, 2048, 512,  probe);

    // Fused QKV projection: grid (32,24) = 768 blocks = 3 blocks/CU.
    // Raw segmented bias (bq|bk|bv) converted in epilogue.
    gemm_bias_kernel<<<dim3(32, 24), 256, 0, stream>>>(
        Xc, WqkvT, bq, bk, bv, QKV, 4096, 3072, 2048, probe, 0, 1.0f);

    // V columns (2560..3071) of QKV -> VT[512][4096]
    transpose_kernel<<<dim3(16, 128), 256, 0, stream>>>(QKV + 2560, VTb, 4096, 3072);

    // Split-key flash: 22 units x 16 heads x 2 batches; partials into dead Xc/WqkvT.
    flash_kernel<<<dim3(22, 16, 2), 256, 0, stream>>>(
        QKV, QKV + 2048, VTb, Ob, PO, PM, PL);

    // Merge split q-tiles (reads partials, writes Ob rows qt>=10).
    combine_kernel<<<dim3(6, 16, 2), 256, 0, stream>>>(PO, PM, PL, Ob);

    // Wo^T into WqkvT region (partials dead after combine).
    tconv_kernel<<<dim3(64, 64), 256, 0, stream>>>(Wo, WqkvT, 2048, 2048, probe);

    gemm_bias_kernel<<<dim3(32, 16), 256, 0, stream>>>(
        Ob, WqkvT, bo, bo, bo, d_out, 4096, 2048, 2048, probe, 1, 1.0f);
}

// Round 8
// 421.299 us; speedup vs baseline: 1.3866x; 1.3866x over previous
//
#include <hip/hip_runtime.h>
#include <math.h>

typedef unsigned short u16;
typedef __bf16 bf16_t;
typedef u16 u16x4 __attribute__((ext_vector_type(4)));
typedef u16 u16x8 __attribute__((ext_vector_type(8)));
typedef bf16_t bf16x8 __attribute__((ext_vector_type(8)));
typedef float f32x4 __attribute__((ext_vector_type(4)));

__device__ __forceinline__ float bf2f(u16 v) {
    union { unsigned u; float f; } x; x.u = ((unsigned)v) << 16; return x.f;
}
// Manual RNE f32->bf16 (exact baseline-522 behavior).
__device__ __forceinline__ u16 f2bf(float f) {
    union { float f; unsigned u; } x; x.f = f;
    unsigned u = x.u;
    return (u16)((u + 0x7fffu + ((u >> 16) & 1u)) >> 16);
}

// Async global->LDS DMA, 16B per lane. LDS dest = wave-uniform base + lane*16
// (hardware-defined); global src is per-lane.
__device__ __forceinline__ void gload16(const u16* g, u16* l) {
    __builtin_amdgcn_global_load_lds(
        (const __attribute__((address_space(1))) void*)g,
        (__attribute__((address_space(3))) void*)l,
        16, 0, 0);
}

// ---------------------------------------------------------------------------
// Runtime dtype detector (probe = Wq). bf16: high byte of each u32 is sign/exp
// in [0x38,0x3F]; fp32: uniform mantissa byte. 64-lane majority => exact.
// ---------------------------------------------------------------------------
__device__ __forceinline__ bool is_bf16_input(const unsigned* __restrict__ probe) {
    unsigned w = probe[(threadIdx.x & 63) * 32771 + 7];
    unsigned b7 = (w >> 8) & 0x7f;
    bool hit = (b7 >= 0x38) && (b7 <= 0x3f);
    return __builtin_popcountll(__ballot(hit)) >= 32;
}

__global__ __launch_bounds__(256) void convert_kernel(
    const void* __restrict__ src, u16* __restrict__ dst, int n,
    const unsigned* __restrict__ probe)
{
    bool bf = is_bf16_input(probe);
    int i = (blockIdx.x * 256 + threadIdx.x) * 8;
    if (i >= n) return;
    if (bf) {
        *(u16x8*)&dst[i] = *(const u16x8*)&((const u16*)src)[i];
    } else {
        const float* s = (const float*)src + i;
        u16x8 o;
#pragma unroll
        for (int j = 0; j < 8; j++) o[j] = f2bf(s[j]);
        *(u16x8*)&dst[i] = o;
    }
}

__global__ __launch_bounds__(256) void tconv_kernel(
    const void* __restrict__ in, u16* __restrict__ out, int R, int C,
    const unsigned* __restrict__ probe)
{
    bool bf = is_bf16_input(probe);
    __shared__ u16 t[32][33];
    int x = threadIdx.x & 31, y = threadIdx.x >> 5;
    int bx = blockIdx.x * 32, by = blockIdx.y * 32;
    if (bf) {
        const u16* s = (const u16*)in;
#pragma unroll
        for (int i = 0; i < 32; i += 8)
            t[y + i][x] = s[(size_t)(by + y + i) * C + bx + x];
    } else {
        const float* s = (const float*)in;
#pragma unroll
        for (int i = 0; i < 32; i += 8)
            t[y + i][x] = f2bf(s[(size_t)(by + y + i) * C + bx + x]);
    }
    __syncthreads();
#pragma unroll
    for (int i = 0; i < 32; i += 8)
        out[(size_t)(bx + y + i) * R + by + x] = t[x][y + i];
}

// Transpose with separate input row stride (pulls V columns out of fused QKV).
__global__ __launch_bounds__(256) void transpose_kernel(
    const u16* __restrict__ in, u16* __restrict__ out, int R, int LD)
{
    __shared__ u16 t[32][33];
    int x = threadIdx.x & 31, y = threadIdx.x >> 5;
    int bx = blockIdx.x * 32, by = blockIdx.y * 32;
#pragma unroll
    for (int i = 0; i < 32; i += 8)
        t[y + i][x] = in[(size_t)(by + y + i) * LD + bx + x];
    __syncthreads();
#pragma unroll
    for (int i = 0; i < 32; i += 8)
        out[(size_t)(bx + y + i) * R + by + x] = t[x][y + i];
}

// ---------------------------------------------------------------------------
// GEMM: C[M,N] = (A[M,K] @ BT[N,K]^T + bias[N]) * scale
// global_load_lds width=16 staging into linear [128][32] LDS tiles.
// Bias read RAW (bf16/f32 via probe); segmented for the fused-QKV call.
// ---------------------------------------------------------------------------
__global__ __launch_bounds__(256) void gemm_bias_kernel(
    const u16* __restrict__ A, const u16* __restrict__ BT,
    const void* __restrict__ bias0, const void* __restrict__ bias1,
    const void* __restrict__ bias2, void* __restrict__ Cout,
    int M, int N, int K, const unsigned* __restrict__ probe,
    int out_native, float scale)
{
    __shared__ __align__(16) u16 As[128 * 32];
    __shared__ __align__(16) u16 Bs[128 * 32];
    const int tid  = threadIdx.x;
    const int lane = tid & 63, wave = tid >> 6;
    const int quad = lane >> 4, li = lane & 15;
    const int bm = blockIdx.x * 128, bn = blockIdx.y * 128;
    const int wm = (wave >> 1) * 64, wn = (wave & 1) * 64;
    const int lrow = lane >> 2;          // 0..15 row within 16-row chunk
    const int lcol = (lane & 3) * 8;     // u16 col offset

    f32x4 acc[4][4] = {};

    for (int k0 = 0; k0 < K; k0 += 32) {
#pragma unroll
        for (int j = 0; j < 2; j++) {
            int c = wave * 2 + j;
            int row = c * 16 + lrow;
            gload16(&A [(size_t)(bm + row) * K + k0 + lcol], &As[c * 16 * 32]);
            gload16(&BT[(size_t)(bn + row) * K + k0 + lcol], &Bs[c * 16 * 32]);
        }
        __syncthreads();   // vmcnt drained at barrier: tiles ready
        bf16x8 af[4], bfr[4];
#pragma unroll
        for (int i = 0; i < 4; i++)
            af[i]  = *(const bf16x8*)&As[(wm + i * 16 + li) * 32 + quad * 8];
#pragma unroll
        for (int i = 0; i < 4; i++)
            bfr[i] = *(const bf16x8*)&Bs[(wn + i * 16 + li) * 32 + quad * 8];
#pragma unroll
        for (int mt = 0; mt < 4; mt++)
#pragma unroll
            for (int nt = 0; nt < 4; nt++)
                acc[mt][nt] = __builtin_amdgcn_mfma_f32_16x16x32_bf16(
                    af[mt], bfr[nt], acc[mt][nt], 0, 0, 0);
        __syncthreads();
    }

    const bool bf_in = is_bf16_input(probe);
    const bool out_bf = out_native ? bf_in : true;
#pragma unroll
    for (int nt = 0; nt < 4; nt++) {
        int col = bn + wn + nt * 16 + li;
        const void* bp; int bc;
        if (col < 2048)      { bp = bias0; bc = col; }
        else if (col < 2560) { bp = bias1; bc = col - 2048; }
        else                 { bp = bias2; bc = col - 2560; }
        float bb = bf_in ? bf2f(((const u16*)bp)[bc]) : ((const float*)bp)[bc];
        if (out_bf) {
            u16* C16 = (u16*)Cout;
#pragma unroll
            for (int mt = 0; mt < 4; mt++)
#pragma unroll
                for (int r = 0; r < 4; r++) {
                    int row = bm + wm + mt * 16 + quad * 4 + r;
                    C16[(size_t)row * N + col] = f2bf((acc[mt][nt][r] + bb) * scale);
                }
        } else {
            float* Cf = (float*)Cout;
#pragma unroll
            for (int mt = 0; mt < 4; mt++)
#pragma unroll
                for (int r = 0; r < 4; r++) {
                    int row = bm + wm + mt * 16 + quad * 4 + r;
                    Cf[(size_t)row * N + col] = (acc[mt][nt][r] + bb) * scale;
                }
        }
    }
}

// ---------------------------------------------------------------------------
// Flash attention v10 = v9 split-key schedule with the VGPR cap REMOVED.
// Round-7 post-mortem: __launch_bounds__(256,4) forced VGPR=64 -> the 64-reg
// oacc spilled to scratch (FETCH 552 MB, WRITE 442 MB, 42% HBM = pure spill
// traffic). The schedule itself worked (Occ 22.6%, correctness passed).
// Plain __launch_bounds__(256) restores the proven ~124-VGPR body; at 29 KB
// LDS that's 3-4 blocks/CU -> the 704-block grid (avg 2.75/CU) stays fully
// co-resident, which is all the split-key schedule needs.
//   - units per (h,b): qt 0..9 -> 1 unit (direct O write); qt 10..15 -> 2
//     units (keys split at halfway tile), unnormalized f32 partials.
//   - combine_kernel merges the 2 partials per split q-tile.
// Partials live in the DEAD Xc+WqkvT workspace region.
// Q:[B*S,3072]  K:[B*S,3072]@+2048  VT:[512,B*S]  O:[B*S,2048].
// ---------------------------------------------------------------------------
__global__ __launch_bounds__(256) void flash_kernel(
    const u16* __restrict__ Q, const u16* __restrict__ Kg,
    const u16* __restrict__ VT, u16* __restrict__ O,
    float* __restrict__ PO, float* __restrict__ PM, float* __restrict__ PL)
{
    constexpr int S = 2048, D = 2048, DH = 128, QKSTR = 3072;
    constexpr float SCALE = 0.08838834764831845f;  // 1/sqrt(128)
    __shared__ __align__(16) u16 Ks[32 * 136];   // [key][dh]   8704 B
    __shared__ __align__(16) u16 Vt[128 * 40];   // [dh][key]  10240 B
    __shared__ __align__(16) u16 Pw[4][32 * 40]; // [qrow][key] 10240 B

    const int tid  = threadIdx.x;
    const int wave = tid >> 6, lane = tid & 63;
    const int quad = lane >> 4, li = lane & 15;
    const int uu = blockIdx.x, h = blockIdx.y, b = blockIdx.z;
    // unit decode: uu 0..9 -> unsplit qt=uu; uu 10..21 -> qt=10+(uu-10)/2,
    // chunk cc=(uu-10)&1 with keys split at the halfway tile.
    const int split = (uu >= 10) ? 1 : 0;
    const int qt = split ? (10 + ((uu - 10) >> 1)) : uu;
    const int cc = split ? ((uu - 10) & 1) : 0;
    const int tiles = qt + 1;
    const int kmid = (tiles >> 1) * 128;
    const int kstart = cc ? kmid : 0;
    const int kend = (split && !cc) ? kmid : tiles * 128;
    const int g = h >> 2;
    const int q0w = qt * 128 + wave * 32;        // this wave's first q-row

    const u16* Qb = Q  + (size_t)b * S * QKSTR;
    const u16* Kb = Kg + (size_t)b * S * QKSTR;
    const u16* Vg = VT + (size_t)g * DH * (2 * S) + (size_t)b * S;

    // Q fragments: B-operand, rows q0w + m*16 + li, k = quad*8 (+c*32)
    bf16x8 qf[2][4];
#pragma unroll
    for (int m = 0; m < 2; m++)
#pragma unroll
        for (int c = 0; c < 4; c++)
            qf[m][c] = *(const bf16x8*)&Qb[(size_t)(q0w + m * 16 + li) * QKSTR
                                           + h * DH + c * 32 + quad * 8];

    f32x4 oacc[2][8] = {};
    float mr[2] = { -INFINITY, -INFINITY };
    float lr[2] = { 0.f, 0.f };

    // --- register prefetch of tile at kstart ---
    u16x8 kreg[2], vreg[2];
#pragma unroll
    for (int ch = 0; ch < 2; ch++) {
        int idx = tid + ch * 256;
        kreg[ch] = *(const u16x8*)&Kb[(size_t)(kstart + (idx >> 4)) * QKSTR
                                      + g * DH + (idx & 15) * 8];
        vreg[ch] = *(const u16x8*)&Vg[(size_t)(idx >> 2) * (2 * S)
                                      + kstart + (idx & 3) * 8];
    }

    for (int kc = kstart; kc < kend; kc += 32) {
        // commit prefetched tile to LDS
#pragma unroll
        for (int ch = 0; ch < 2; ch++) {
            int idx = tid + ch * 256;
            *(u16x8*)&Ks[(idx >> 4) * 136 + (idx & 15) * 8] = kreg[ch];
            *(u16x8*)&Vt[(idx >> 2) * 40  + (idx & 3) * 8]  = vreg[ch];
        }
        __syncthreads();

        // issue prefetch for next tile (overlaps with compute below)
        int kn = kc + 32;
        if (kn < kend) {
#pragma unroll
            for (int ch = 0; ch < 2; ch++) {
                int idx = tid + ch * 256;
                kreg[ch] = *(const u16x8*)&Kb[(size_t)(kn + (idx >> 4)) * QKSTR
                                              + g * DH + (idx & 15) * 8];
                vreg[ch] = *(const u16x8*)&Vg[(size_t)(idx >> 2) * (2 * S)
                                              + kn + (idx & 3) * 8];
            }
        }

        if (kc <= q0w) {   // causal: tiles with kc > q0w are fully masked
            // S^T = K · Q^T : sacc[m][t], C row = key (quad*4+r), col = qrow (li)
            f32x4 sacc[2][2] = {};
#pragma unroll
            for (int t = 0; t < 2; t++)
#pragma unroll
                for (int c = 0; c < 4; c++) {
                    bf16x8 kf = *(const bf16x8*)&Ks[(t * 16 + li) * 136 + c * 32 + quad * 8];
#pragma unroll
                    for (int m = 0; m < 2; m++)
                        sacc[m][t] = __builtin_amdgcn_mfma_f32_16x16x32_bf16(
                            kf, qf[m][c], sacc[m][t], 0, 0, 0);
                }

            float alpha_b[2][4];
#pragma unroll
            for (int m = 0; m < 2; m++) {
                int row = q0w + m * 16 + li;
                f32x4 s0 = sacc[m][0] * SCALE;
                f32x4 s1 = sacc[m][1] * SCALE;
#pragma unroll
                for (int r = 0; r < 4; r++) {
                    int k0 = kc + quad * 4 + r;
                    if (k0 > row)      s0[r] = -INFINITY;
                    if (k0 + 16 > row) s1[r] = -INFINITY;
                }
                float mx = fmaxf(fmaxf(fmaxf(s0[0], s0[1]), fmaxf(s0[2], s0[3])),
                                 fmaxf(fmaxf(s1[0], s1[1]), fmaxf(s1[2], s1[3])));
                mx = fmaxf(mx, __shfl_xor(mx, 16));
                mx = fmaxf(mx, __shfl_xor(mx, 32));
                float mnew = fmaxf(mr[m], mx);
                float al = __expf(mr[m] - mnew);
                mr[m] = mnew;
                f32x4 p0, p1;
                float ps = 0.f;
#pragma unroll
                for (int r = 0; r < 4; r++) {
                    p0[r] = __expf(s0[r] - mnew);
                    p1[r] = __expf(s1[r] - mnew);
                    ps += p0[r] + p1[r];
                }
                ps += __shfl_xor(ps, 16);
                ps += __shfl_xor(ps, 32);
                lr[m] = lr[m] * al + ps;
                u16x4 c0, c1;
#pragma unroll
                for (int r = 0; r < 4; r++) { c0[r] = f2bf(p0[r]); c1[r] = f2bf(p1[r]); }
                *(u16x4*)&Pw[wave][(m * 16 + li) * 40 + quad * 4]      = c0;
                *(u16x4*)&Pw[wave][(m * 16 + li) * 40 + 16 + quad * 4] = c1;
#pragma unroll
                for (int r = 0; r < 4; r++)
                    alpha_b[m][r] = __shfl(al, quad * 4 + r, 16);
            }

            // rescale O accumulators
#pragma unroll
            for (int m = 0; m < 2; m++)
#pragma unroll
                for (int dt = 0; dt < 8; dt++)
#pragma unroll
                    for (int r = 0; r < 4; r++)
                        oacc[m][dt][r] *= alpha_b[m][r];

            // drain P stores (same wave) before vector re-read
            asm volatile("s_waitcnt lgkmcnt(0)" ::: "memory");
            union { u16x8 u; bf16x8 bv; } pc0, pc1;
            pc0.u = *(const u16x8*)&Pw[wave][(0 * 16 + li) * 40 + quad * 8];
            pc1.u = *(const u16x8*)&Pw[wave][(1 * 16 + li) * 40 + quad * 8];
            bf16x8 pf[2] = { pc0.bv, pc1.bv };

            // O += P · V
#pragma unroll
            for (int dt = 0; dt < 8; dt++) {
                bf16x8 vf = *(const bf16x8*)&Vt[(dt * 16 + li) * 40 + quad * 8];
#pragma unroll
                for (int m = 0; m < 2; m++)
                    oacc[m][dt] = __builtin_amdgcn_mfma_f32_16x16x32_bf16(
                        pf[m], vf, oacc[m][dt], 0, 0, 0);
            }
        }
        __syncthreads();
    }

    if (!split) {
        u16* Ob = O + (size_t)b * S * D;
#pragma unroll
        for (int m = 0; m < 2; m++) {
#pragma unroll
            for (int r = 0; r < 4; r++) {
                float linv = 1.0f / __shfl(lr[m], quad * 4 + r, 16);
                int row = q0w + m * 16 + quad * 4 + r;
#pragma unroll
                for (int dt = 0; dt < 8; dt++)
                    Ob[(size_t)row * D + h * DH + dt * 16 + li] =
                        f2bf(oacc[m][dt][r] * linv);
            }
        }
    } else {
        // partial epilogue: unnormalized O (f32) + per-row m, l
        const int gu = (b * 16 + h) * 12 + (qt - 10) * 2 + cc;
        float* POu = PO + (size_t)gu * 16384;
#pragma unroll
        for (int m = 0; m < 2; m++)
#pragma unroll
            for (int r = 0; r < 4; r++) {
                int rl = wave * 32 + m * 16 + quad * 4 + r;
#pragma unroll
                for (int dt = 0; dt < 8; dt++)
                    POu[rl * 128 + dt * 16 + li] = oacc[m][dt][r];
            }
        if (quad == 0) {
#pragma unroll
            for (int m = 0; m < 2; m++) {
                int rl = wave * 32 + m * 16 + li;   // mr/lr are per-li rows
                PM[gu * 128 + rl] = mr[m];
                PL[gu * 128 + rl] = lr[m];
            }
        }
    }
}

// ---------------------------------------------------------------------------
// Merge the 2 key-chunk partials of each split q-tile (qt 10..15):
// O = (e^{m0-M} O_0 + e^{m1-M} O_1) / (e^{m0-M} l_0 + e^{m1-M} l_1).
// Grid (6, 16, 2) x 256 thr; thread -> (row = t>>1, col-half = (t&1)*64).
// ---------------------------------------------------------------------------
__global__ __launch_bounds__(256) void combine_kernel(
    const float* __restrict__ PO, const float* __restrict__ PM,
    const float* __restrict__ PL, u16* __restrict__ O)
{
    constexpr int S = 2048, D = 2048;
    const int qt = 10 + blockIdx.x, h = blockIdx.y, b = blockIdx.z;
    const int g0 = (b * 16 + h) * 12 + blockIdx.x * 2;
    const int t = threadIdx.x;
    const int row = t >> 1, half = (t & 1) * 64;

    float m0 = PM[g0 * 128 + row], m1 = PM[(g0 + 1) * 128 + row];
    float l0 = PL[g0 * 128 + row], l1 = PL[(g0 + 1) * 128 + row];
    float M = fmaxf(m0, m1);
    float w0 = __expf(m0 - M), w1 = __expf(m1 - M);
    float linv = 1.0f / (l0 * w0 + l1 * w1);

    const float* p0 = PO + (size_t)g0 * 16384 + row * 128 + half;
    const float* p1 = p0 + 16384;
    u16* out = O + (size_t)(b * S + qt * 128 + row) * D + h * 128 + half;
#pragma unroll
    for (int j = 0; j < 64; j += 4) {
        f32x4 a = *(const f32x4*)&p0[j];
        f32x4 c = *(const f32x4*)&p1[j];
        u16x4 o;
#pragma unroll
        for (int e = 0; e < 4; e++) o[e] = f2bf((a[e] * w0 + c[e] * w1) * linv);
        *(u16x4*)&out[j] = o;
    }
}

// ---------------------------------------------------------------------------
extern "C" void kernel_launch(void* const* d_in, const int* in_sizes, int n_in,
                              void* d_out, int out_size, void* d_ws, size_t ws_size,
                              hipStream_t stream)
{
    const void* X  = d_in[0];
    const void* Wq = d_in[3];
    const void* bq = d_in[4];
    const void* Wk = d_in[5];
    const void* bk = d_in[6];
    const void* Wv = d_in[7];
    const void* bv = d_in[8];
    const void* Wo = d_in[9];
    const void* bo = d_in[10];
    const unsigned* probe = (const unsigned*)d_in[3];

    u16* ws    = (u16*)d_ws;
    u16* Xc    = ws;                     // [0, 8388608)        X bf16
    u16* WqkvT = Xc    + 8388608;        // [8388608, 14680064) Wqkv^T / later WoT
    u16* QKV   = WqkvT + 6291456;        // [14680064, 27262976)
    u16* VTb   = QKV   + 12582912;       // [27262976, 29360128)
    u16* Ob    = VTb   + 2097152;        // [29360128, 37748736)
    // Partials overlay the DEAD Xc+WqkvT region during flash+combine:
    // PO f32[384*16384] + PM f32[384*128] + PL f32[384*128] = 12,779,520 u16.
    float* PO  = (float*)ws;
    float* PM  = PO + 384 * 16384;
    float* PL  = PM + 384 * 128;

    convert_kernel<<<4096, 256, 0, stream>>>(X, Xc, 8388608, probe);

    // Wqkv^T[3072][2048]: rows 0..2047 = Wq^T, 2048..2559 = Wk^T, 2560..3071 = Wv^T
    tconv_kernel<<<dim3(64, 64), 256, 0, stream>>>(Wq, WqkvT,               2048, 2048, probe);
    tconv_kernel<<<dim3(16, 64), 256, 0, stream>>>(Wk, WqkvT + 2048 * 2048, 2048, 512,  probe);
    tconv_kernel<<<dim3(16, 64), 256, 0, stream>>>(Wv, WqkvT + 2560 * 2048, 2048, 512,  probe);

    // Fused QKV projection: grid (32,24) = 768 blocks = 3 blocks/CU.
    gemm_bias_kernel<<<dim3(32, 24), 256, 0, stream>>>(
        Xc, WqkvT, bq, bk, bv, QKV, 4096, 3072, 2048, probe, 0, 1.0f);

    // V columns (2560..3071) of QKV -> VT[512][4096]
    transpose_kernel<<<dim3(16, 128), 256, 0, stream>>>(QKV + 2560, VTb, 4096, 3072);

    // Split-key flash: 22 units x 16 heads x 2 batches; partials into dead Xc/WqkvT.
    flash_kernel<<<dim3(22, 16, 2), 256, 0, stream>>>(
        QKV, QKV + 2048, VTb, Ob, PO, PM, PL);

    // Merge split q-tiles (reads partials, writes Ob rows qt>=10).
    combine_kernel<<<dim3(6, 16, 2), 256, 0, stream>>>(PO, PM, PL, Ob);

    // Wo^T into WqkvT region (partials dead after combine).
    tconv_kernel<<<dim3(64, 64), 256, 0, stream>>>(Wo, WqkvT, 2048, 2048, probe);

    gemm_bias_kernel<<<dim3(32, 16), 256, 0, stream>>>(
        Ob, WqkvT, bo, bo, bo, d_out, 4096, 2048, 2048, probe, 1, 1.0f);
}